// Round 1
// baseline (1784.210 us; speedup 1.0000x reference)
//
#include <hip/hip_runtime.h>

// MCTransformer: x+pe -> QKV proj (relu, q*D^-0.5) -> softmax(qk^T) -> attn@v
//                -> residual + LayerNorm. Outputs: x_out [8192,10,1024] f32, attn [8192,10,10] f32.
//
// Strategy: fp16 MFMA GEMM (M=81920, N=3072, K=1024) in the m97 structure
// (128x128 tile, BK=32, global_load_lds width=16), then per-batch attention+LN.

typedef __attribute__((ext_vector_type(8))) _Float16 h8_t;
typedef __attribute__((ext_vector_type(4))) _Float16 h4_t;
typedef __attribute__((ext_vector_type(4))) float f32x4_t;

#define B_DIM 8192
#define T_DIM 10
#define D_DIM 1024
#define M_DIM (B_DIM * T_DIM)   // 81920
#define N_DIM (3 * D_DIM)       // 3072
#define K_DIM D_DIM             // 1024

// ---------------- prep: weights fp32 -> fp16, concat q|k|v ----------------
__global__ void prep_w(const float* __restrict__ Wq, const float* __restrict__ Wk,
                       const float* __restrict__ Wv, const float* __restrict__ bq,
                       const float* __restrict__ bk, const float* __restrict__ bv,
                       _Float16* __restrict__ Wc, float* __restrict__ biasc) {
    int idx = blockIdx.x * 256 + threadIdx.x;          // 0 .. 3072*1024-1
    int n = idx >> 10;
    int d = idx & 1023;
    const float* src = (n < 1024) ? Wq : (n < 2048) ? Wk : Wv;
    Wc[idx] = (_Float16)src[(n & 1023) * 1024 + d];
    if (idx < 3072) {
        const float* bsrc = (idx < 1024) ? bq : (idx < 2048) ? bk : bv;
        biasc[idx] = bsrc[idx & 1023];
    }
}

// ---------------- prep: xpe = fp16(x + pe) ----------------
__global__ void prep_x(const float* __restrict__ x, const float* __restrict__ pe,
                       _Float16* __restrict__ xpe) {
    int i4 = blockIdx.x * 256 + threadIdx.x;           // float4 index
    int eidx = i4 * 4;
    int row = eidx >> 10;                              // m = b*10 + t
    int t = row % 10;
    int d = eidx & 1023;
    float4 xv = *(const float4*)(x + eidx);
    float4 pv = *(const float4*)(pe + (t << 10) + d);
    h4_t o = { (_Float16)(xv.x + pv.x), (_Float16)(xv.y + pv.y),
               (_Float16)(xv.z + pv.z), (_Float16)(xv.w + pv.w) };
    *(h4_t*)(xpe + eidx) = o;
}

// ---------------- GEMM: qkv = relu(xpe @ Wc^T + bias), q scaled ----------------
__device__ __forceinline__ void load_lds16(const _Float16* g, _Float16* l) {
    // LDS dest is wave-uniform base; HW scatters lane i -> base + i*16B.
    __builtin_amdgcn_global_load_lds((const __attribute__((address_space(1))) void*)g,
                                     (__attribute__((address_space(3))) void*)l,
                                     16, 0, 0);
}

__global__ __launch_bounds__(256) void gemm_qkv(const _Float16* __restrict__ A,   // [M][K]
                                                const _Float16* __restrict__ Bt,  // [N][K]
                                                const float* __restrict__ bias,   // [N]
                                                _Float16* __restrict__ qkv) {     // [M][N]
    __shared__ _Float16 lA[128 * 32];   // row-major [128][32], lane-contiguous for global_load_lds
    __shared__ _Float16 lB[128 * 32];
    const int tid = threadIdx.x;
    const int wave = tid >> 6, lane = tid & 63;
    const int quad = lane >> 4, l16 = lane & 15;
    const int m0 = blockIdx.y * 128, n0 = blockIdx.x * 128;
    const int wm = (wave >> 1) * 64, wn = (wave & 1) * 64;

    // staging: each wave issues 2 A + 2 B async loads of 1024B per K-iter.
    // lane i loads 16B chunk (lane&3) of tile-row (wave*32 + q*16 + (lane>>2)).
    const _Float16* ga0 = A  + (size_t)(m0 + wave * 32 + (lane >> 2)) * K_DIM + (lane & 3) * 8;
    const _Float16* gb0 = Bt + (size_t)(n0 + wave * 32 + (lane >> 2)) * K_DIM + (lane & 3) * 8;
    _Float16* la0 = lA + wave * 1024;   // uniform base per wave-instr
    _Float16* lb0 = lB + wave * 1024;

    // fragment LDS element offsets (A-operand: row m=l16-based, k=quad*8..+7 contiguous)
    int aoff[4], boff[4];
#pragma unroll
    for (int i = 0; i < 4; i++) {
        aoff[i] = (wm + i * 16 + l16) * 32 + quad * 8;
        boff[i] = (wn + i * 16 + l16) * 32 + quad * 8;
    }

    f32x4_t acc[4][4] = {};

    for (int kt = 0; kt < K_DIM; kt += 32) {
        __syncthreads();                         // prior iter's ds_reads done
        load_lds16(ga0 + kt, la0);
        load_lds16(ga0 + 16 * K_DIM + kt, la0 + 512);
        load_lds16(gb0 + kt, lb0);
        load_lds16(gb0 + 16 * K_DIM + kt, lb0 + 512);
        __syncthreads();                         // vmcnt drain + visibility

        h8_t af[4], bf[4];
#pragma unroll
        for (int i = 0; i < 4; i++) af[i] = *(const h8_t*)(lA + aoff[i]);
#pragma unroll
        for (int j = 0; j < 4; j++) bf[j] = *(const h8_t*)(lB + boff[j]);
#pragma unroll
        for (int i = 0; i < 4; i++)
#pragma unroll
            for (int j = 0; j < 4; j++)
                acc[i][j] = __builtin_amdgcn_mfma_f32_16x16x32_f16(af[i], bf[j], acc[i][j], 0, 0, 0);
    }

    // epilogue: bias + relu (+ q scale), store fp16. C/D layout: row=quad*4+r, col=l16.
#pragma unroll
    for (int j = 0; j < 4; j++) {
        int ncol = n0 + wn + j * 16 + l16;
        float bi = bias[ncol];
        float sc = (ncol < 1024) ? 0.03125f : 1.0f;   // D^-0.5 on q only
#pragma unroll
        for (int i = 0; i < 4; i++) {
            int mrow = m0 + wm + i * 16 + quad * 4;
#pragma unroll
            for (int r = 0; r < 4; r++) {
                float v = fmaxf(acc[i][j][r] + bi, 0.0f) * sc;
                qkv[(size_t)(mrow + r) * N_DIM + ncol] = (_Float16)v;
            }
        }
    }
}

// ---------------- attention + residual + LayerNorm, one block per batch ----------------
__global__ __launch_bounds__(256) void attn_ln(const _Float16* __restrict__ qkv,
                                               const float* __restrict__ x,
                                               const float* __restrict__ pe,
                                               const float* __restrict__ gamma,
                                               const float* __restrict__ beta,
                                               float* __restrict__ xout,
                                               float* __restrict__ attnout) {
    __shared__ __align__(16) _Float16 sq[10 * 1024];
    __shared__ __align__(16) _Float16 sk[10 * 1024];
    __shared__ __align__(16) _Float16 sv[10 * 1024];
    __shared__ float sS[100];
    __shared__ float sP[100];
    const int tid = threadIdx.x;
    const int wave = tid >> 6, lane = tid & 63;
    const int b = blockIdx.x;
    const size_t base = (size_t)b * 10 * N_DIM;   // 10 rows of 3072 are contiguous

    // stage q,k,v into LDS: 30720 fp16 = 3840 x 16B chunks, 15 per thread
#pragma unroll
    for (int c = 0; c < 15; c++) {
        int ch = c * 256 + tid;
        int row = ch / 384;                       // 384 chunks per 3072-row
        int col = (ch - row * 384) * 8;
        uint4 val = *(const uint4*)(qkv + base + (size_t)ch * 8);
        _Float16* dst = (col < 1024) ? sq : (col < 2048) ? sk : sv;
        *(uint4*)(dst + row * 1024 + (col & 1023)) = val;
    }
    __syncthreads();

    // S[t][s] = q[t] . k[s]  (q already scaled by D^-0.5) — wave per pair
    for (int p = wave; p < 100; p += 4) {
        int t = p / 10, s = p - (p / 10) * 10;
        const _Float16* qrow = sq + t * 1024;
        const _Float16* krow = sk + s * 1024;
        float sum = 0.0f;
#pragma unroll
        for (int i = 0; i < 2; i++) {
            int e = i * 512 + lane * 8;
            h8_t q8 = *(const h8_t*)(qrow + e);
            h8_t k8 = *(const h8_t*)(krow + e);
#pragma unroll
            for (int j = 0; j < 8; j++) sum += (float)q8[j] * (float)k8[j];
        }
#pragma unroll
        for (int off = 32; off > 0; off >>= 1) sum += __shfl_xor(sum, off);
        if (lane == 0) sS[p] = sum;
    }
    __syncthreads();

    // softmax over s (threads 0..9), write attn output
    if (tid < 10) {
        float mx = -1e30f;
#pragma unroll
        for (int s = 0; s < 10; s++) mx = fmaxf(mx, sS[tid * 10 + s]);
        float ex[10], sum = 0.0f;
#pragma unroll
        for (int s = 0; s < 10; s++) { ex[s] = __expf(sS[tid * 10 + s] - mx); sum += ex[s]; }
        float inv = 1.0f / sum;
#pragma unroll
        for (int s = 0; s < 10; s++) {
            float pp = ex[s] * inv;
            sP[tid * 10 + s] = pp;
            attnout[(size_t)b * 100 + tid * 10 + s] = pp;
        }
    }
    __syncthreads();

    // out = P @ v, residual (x+pe recomputed in fp32), LayerNorm per row — wave per row t
    for (int t = wave; t < 10; t += 4) {
        float pr[10];
#pragma unroll
        for (int s = 0; s < 10; s++) pr[s] = sP[t * 10 + s];
        float xr[16];
        float sum = 0.0f, sumsq = 0.0f;
#pragma unroll
        for (int i = 0; i < 16; i++) {
            int e = i * 64 + lane;
            float o = 0.0f;
#pragma unroll
            for (int s = 0; s < 10; s++) o += pr[s] * (float)sv[s * 1024 + e];
            float xv = x[((size_t)b * 10 + t) * 1024 + e] + pe[t * 1024 + e];
            float v = xv + o;
            xr[i] = v; sum += v; sumsq += v * v;
        }
#pragma unroll
        for (int off = 32; off > 0; off >>= 1) {
            sum += __shfl_xor(sum, off);
            sumsq += __shfl_xor(sumsq, off);
        }
        float mu = sum * (1.0f / 1024.0f);
        float var = sumsq * (1.0f / 1024.0f) - mu * mu;
        float rs = rsqrtf(var + 1e-5f);
#pragma unroll
        for (int i = 0; i < 16; i++) {
            int e = i * 64 + lane;
            xout[((size_t)b * 10 + t) * 1024 + e] = (xr[i] - mu) * rs * gamma[e] + beta[e];
        }
    }
}

// ---------------- launch ----------------
extern "C" void kernel_launch(void* const* d_in, const int* in_sizes, int n_in,
                              void* d_out, int out_size, void* d_ws, size_t ws_size,
                              hipStream_t stream) {
    const float* x     = (const float*)d_in[0];
    const float* pe    = (const float*)d_in[1];
    const float* Wq    = (const float*)d_in[2];
    const float* bq    = (const float*)d_in[3];
    const float* Wk    = (const float*)d_in[4];
    const float* bk    = (const float*)d_in[5];
    const float* Wv    = (const float*)d_in[6];
    const float* bv    = (const float*)d_in[7];
    const float* gamma = (const float*)d_in[8];
    const float* beta  = (const float*)d_in[9];

    float* xout    = (float*)d_out;
    float* attnout = xout + (size_t)M_DIM * D_DIM;   // outputs concatenated: x then attn

    // workspace layout (bytes):
    //   xpe  fp16 [81920][1024] : [0,          167772160)
    //   Wc   fp16 [3072][1024]  : [167772160,  174063616)
    //   bias f32  [3072]        : [174063616,  174075904)
    //   qkv  fp16 [81920][3072] : [174075904,  677392384)
    char* ws = (char*)d_ws;
    _Float16* xpe   = (_Float16*)ws;
    _Float16* Wc    = (_Float16*)(ws + 167772160);
    float*    biasc = (float*)   (ws + 174063616);
    _Float16* qkv   = (_Float16*)(ws + 174075904);

    prep_w<<<dim3((N_DIM * K_DIM) / 256), 256, 0, stream>>>(Wq, Wk, Wv, bq, bk, bv, Wc, biasc);
    prep_x<<<dim3((M_DIM * D_DIM) / 1024), 256, 0, stream>>>(x, pe, xpe);
    gemm_qkv<<<dim3(N_DIM / 128, M_DIM / 128), 256, 0, stream>>>(xpe, Wc, biasc, qkv);
    attn_ln<<<dim3(B_DIM), 256, 0, stream>>>(qkv, x, pe, gamma, beta, xout, attnout);
}